// Round 1
// baseline (770.257 us; speedup 1.0000x reference)
//
#include <hip/hip_runtime.h>

#define NN 50000
#define NE 800000
#define KIN 512
#define HC 128

typedef float f32x4 __attribute__((ext_vector_type(4)));
typedef float f32x2 __attribute__((ext_vector_type(2)));
typedef short s16x8 __attribute__((ext_vector_type(8)));

__device__ __forceinline__ ushort f2bf(float f) {
  unsigned u = __float_as_uint(f);
  unsigned r = (u + 0x7FFFu + ((u >> 16) & 1u)) >> 16;  // RNE
  return (ushort)r;
}

// deg init to 1.0 (self loop) + W transpose/convert: Wt[c][k] bf16
__global__ void k_prep(const float* __restrict__ W, float* __restrict__ deg,
                       ushort* __restrict__ Wt) {
  int t = blockIdx.x * 256 + threadIdx.x;   // t < 65536
  if (t < NN) deg[t] = 1.0f;
  if (t < KIN * HC) {
    int c = t & (HC - 1), k = t >> 7;       // W row-major [k][c]
    Wt[c * KIN + k] = f2bf(W[t]);
  }
}

__global__ void k_deg(const int* __restrict__ ei, float* __restrict__ deg) {
  int e = blockIdx.x * 256 + threadIdx.x;
  if (e < NE) atomicAdd(&deg[ei[NE + e]], 1.0f);
}

__global__ void k_dinv(float* __restrict__ deg) {
  int i = blockIdx.x * 256 + threadIdx.x;
  if (i < NN) deg[i] = rsqrtf(deg[i]);      // deg >= 1 always
}

// x = feats @ W   (bf16 MFMA, f32 accumulate, f32 out)
// BM=128, BN=128(=H), BK=64. 4 waves in 2x2, each wave 64x64 via 4x4 frags.
__launch_bounds__(256, 2)
__global__ void k_gemm(const float* __restrict__ feats, const ushort* __restrict__ Wt,
                       float* __restrict__ x) {
  __shared__ ushort Abuf[128 * 64];         // row stride 128B, XOR-swizzled
  const int tid = threadIdx.x;
  const int lane = tid & 63;
  const int wid = tid >> 6;
  const int wr = wid >> 1, wc = wid & 1;
  const int rbase = blockIdx.x * 128;

  f32x4 acc[4][4];
#pragma unroll
  for (int a = 0; a < 4; a++)
#pragma unroll
    for (int b2 = 0; b2 < 4; b2++) acc[a][b2] = f32x4{0.f, 0.f, 0.f, 0.f};

  // staging coords: 2 threads per row, 32 f32 each
  const int sr = tid >> 1;
  const int sk = (tid & 1) * 32;
  int grow = rbase + sr; if (grow > NN - 1) grow = NN - 1;  // clamp (junk rows unstored)
  const float* gsrc = feats + grow * KIN + sk;

  for (int ks = 0; ks < KIN; ks += 64) {
    f32x4 v[8];
#pragma unroll
    for (int q = 0; q < 8; q++) v[q] = *(const f32x4*)(gsrc + ks + q * 4);
    __syncthreads();                        // prev-iter LDS reads done
#pragma unroll
    for (int q8 = 0; q8 < 4; q8++) {
      s16x8 pk;
#pragma unroll
      for (int t2 = 0; t2 < 4; t2++) {
        pk[t2]     = (short)f2bf(v[2 * q8][t2]);
        pk[t2 + 4] = (short)f2bf(v[2 * q8 + 1][t2]);
      }
      int kb = (sk >> 3) + q8;              // 16B block index within row
      int boff = sr * 128 + ((kb ^ (sr & 7)) << 4);
      *(s16x8*)((char*)Abuf + boff) = pk;
    }
    __syncthreads();
#pragma unroll
    for (int kk = 0; kk < 2; kk++) {
      s16x8 af[4];
#pragma unroll
      for (int mt = 0; mt < 4; mt++) {
        int r = wr * 64 + mt * 16 + (lane & 15);
        int kb = kk * 4 + (lane >> 4);
        af[mt] = *(const s16x8*)((const char*)Abuf + r * 128 + ((kb ^ (r & 7)) << 4));
      }
#pragma unroll
      for (int nt = 0; nt < 4; nt++) {
        int c = wc * 64 + nt * 16 + (lane & 15);
        const s16x8 bf = *(const s16x8*)(Wt + c * KIN + (ks + kk * 32 + (lane >> 4) * 8));
#pragma unroll
        for (int mt = 0; mt < 4; mt++)
          acc[mt][nt] = __builtin_amdgcn_mfma_f32_16x16x32_bf16(af[mt], bf, acc[mt][nt], 0, 0, 0);
      }
    }
  }
  // C/D frag: col = lane&15 (n), row = (lane>>4)*4 + j (m)
#pragma unroll
  for (int mt = 0; mt < 4; mt++) {
    int r0 = rbase + wr * 64 + mt * 16 + (lane >> 4) * 4;
#pragma unroll
    for (int nt = 0; nt < 4; nt++) {
      int c = wc * 64 + nt * 16 + (lane & 15);
#pragma unroll
      for (int j = 0; j < 4; j++) {
        int r = r0 + j;
        if (r < NN) x[r * HC + c] = acc[mt][nt][j];
      }
    }
  }
}

// out = x * dinv^2 (self loop) + b
__global__ void k_self(const float* __restrict__ x, const float* __restrict__ dinv,
                       const float* __restrict__ b, float* __restrict__ out) {
  int i = blockIdx.x * 256 + threadIdx.x;   // float4 index
  if (i >= NN * HC / 4) return;
  int n = i >> 5;                           // 32 float4 per row
  float s = dinv[n]; s = s * s;
  f32x4 v = ((const f32x4*)x)[i];
  f32x4 bb = ((const f32x4*)b)[i & 31];
  ((f32x4*)out)[i] = v * s + bb;
}

// out[dst] += x[src] * dinv[src]*dinv[dst], one wave per edge
__global__ void k_edge(const int* __restrict__ ei, const float* __restrict__ x,
                       const float* __restrict__ dinv, float* __restrict__ out) {
  int e = blockIdx.x * 4 + (threadIdx.x >> 6);
  if (e >= NE) return;
  int lane = threadIdx.x & 63;
  int s = ei[e], d = ei[NE + e];
  float nrm = dinv[s] * dinv[d];
  f32x2 v = *(const f32x2*)(x + s * HC + lane * 2);
  float* o = out + d * HC + lane * 2;
  atomicAdd(o, v.x * nrm);
  atomicAdd(o + 1, v.y * nrm);
}

// relu + JAX threefry2x32-20 dropout (partitionable path: ctr=(0,i), bits=o0^o1)
__global__ void k_final(float* __restrict__ out) {
  int i = blockIdx.x * 256 + threadIdx.x;
  if (i >= NN * HC) return;
  unsigned x0 = 0u, x1 = (unsigned)i;
  const unsigned ks0 = 0u, ks1 = 42u, ks2 = 0x1BD11BDAu ^ 42u;
  x0 += ks0; x1 += ks1;
#define R(r) { x0 += x1; x1 = (x1 << r) | (x1 >> (32 - r)); x1 ^= x0; }
  R(13) R(15) R(26) R(6)
  x0 += ks1; x1 += ks2 + 1u;
  R(17) R(29) R(16) R(24)
  x0 += ks2; x1 += ks0 + 2u;
  R(13) R(15) R(26) R(6)
  x0 += ks0; x1 += ks1 + 3u;
  R(17) R(29) R(16) R(24)
  x0 += ks1; x1 += ks2 + 4u;
  R(13) R(15) R(26) R(6)
  x0 += ks2; x1 += ks0 + 5u;
#undef R
  unsigned bits = x0 ^ x1;
  float v = fmaxf(out[i], 0.0f) * 2.0f;     // h / keep, keep = 0.5
  out[i] = (bits >> 31) ? 0.0f : v;         // uniform < 0.5  <=>  top bit 0
}

extern "C" void kernel_launch(void* const* d_in, const int* in_sizes, int n_in,
                              void* d_out, int out_size, void* d_ws, size_t ws_size,
                              hipStream_t stream) {
  const float* feats = (const float*)d_in[0];
  const float* W     = (const float*)d_in[1];
  const float* b     = (const float*)d_in[2];
  const int*   ei    = (const int*)d_in[3];   // int32 (jax x64 disabled)
  float* out = (float*)d_out;

  // ws layout: x[NN*HC] f32 | deg/dinv[NN] f32 | Wt[HC*KIN] bf16   (~26 MB)
  char* ws = (char*)d_ws;
  float*  x   = (float*)ws;
  size_t  off = ((size_t)NN * HC * 4 + 255) & ~(size_t)255;
  float*  deg = (float*)(ws + off);
  off += ((size_t)NN * 4 + 255) & ~(size_t)255;
  ushort* Wt  = (ushort*)(ws + off);

  k_prep<<<(KIN * HC + 255) / 256, 256, 0, stream>>>(W, deg, Wt);
  k_deg <<<(NE + 255) / 256, 256, 0, stream>>>(ei, deg);
  k_dinv<<<(NN + 255) / 256, 256, 0, stream>>>(deg);
  k_gemm<<<(NN + 127) / 128, 256, 0, stream>>>(feats, Wt, x);
  k_self<<<(NN * HC / 4 + 255) / 256, 256, 0, stream>>>(x, deg, b, out);
  k_edge<<<(NE + 3) / 4, 256, 0, stream>>>(ei, x, deg, out);
  k_final<<<(NN * HC + 255) / 256, 256, 0, stream>>>(out);
}

// Round 2
// 337.547 us; speedup vs baseline: 2.2819x; 2.2819x over previous
//
#include <hip/hip_runtime.h>

#define NN 50000
#define NE 800000
#define KIN 512
#define HC 128

typedef float f32x4 __attribute__((ext_vector_type(4)));
typedef float f32x2 __attribute__((ext_vector_type(2)));
typedef short s16x8 __attribute__((ext_vector_type(8)));

__device__ __forceinline__ ushort f2bf(float f) {
  unsigned u = __float_as_uint(f);
  unsigned r = (u + 0x7FFFu + ((u >> 16) & 1u)) >> 16;  // RNE
  return (ushort)r;
}

// JAX threefry2x32-20, partitionable path: ctr=(0,i), key=(0,42), bits=o0^o1
__device__ __forceinline__ unsigned tf_bits(unsigned i) {
  unsigned x0 = 0u, x1 = i;
  const unsigned ks0 = 0u, ks1 = 42u, ks2 = 0x1BD11BDAu ^ 42u;
  x0 += ks0; x1 += ks1;
#define R(r) { x0 += x1; x1 = (x1 << r) | (x1 >> (32 - r)); x1 ^= x0; }
  R(13) R(15) R(26) R(6)
  x0 += ks1; x1 += ks2 + 1u;
  R(17) R(29) R(16) R(24)
  x0 += ks2; x1 += ks0 + 2u;
  R(13) R(15) R(26) R(6)
  x0 += ks0; x1 += ks1 + 3u;
  R(17) R(29) R(16) R(24)
  x0 += ks1; x1 += ks2 + 4u;
  R(13) R(15) R(26) R(6)
  x0 += ks2; x1 += ks0 + 5u;
#undef R
  return x0 ^ x1;
}

// zero edge-count + W transpose/convert: Wt[c][k] bf16
__global__ void k_prep(const float* __restrict__ W, int* __restrict__ cnt,
                       ushort* __restrict__ Wt) {
  int t = blockIdx.x * 256 + threadIdx.x;   // t < 65536
  if (t < NN) cnt[t] = 0;
  if (t < KIN * HC) {
    int c = t & (HC - 1), k = t >> 7;       // W row-major [k][c]
    Wt[c * KIN + k] = f2bf(W[t]);
  }
}

__global__ void k_cnt(const int* __restrict__ ei, int* __restrict__ cnt) {
  int e = blockIdx.x * 256 + threadIdx.x;
  if (e < NE) atomicAdd(&cnt[ei[NE + e]], 1);
}

// single-workgroup exclusive scan of cnt -> off[NN+1]; dinv = rsqrt(cnt+1)
__global__ void k_scan(const int* __restrict__ cnt, int* __restrict__ off,
                       float* __restrict__ dinv) {
  __shared__ int part[1024];
  const int t = threadIdx.x;
  const int PER = (NN + 1023) / 1024;       // 49
  const int base = t * PER;
  int sum = 0;
  for (int i = 0; i < PER; i++) {
    int idx = base + i;
    if (idx < NN) sum += cnt[idx];
  }
  part[t] = sum;
  __syncthreads();
  for (int d = 1; d < 1024; d <<= 1) {
    int v = 0;
    if (t >= d) v = part[t - d];
    __syncthreads();
    if (t >= d) part[t] += v;
    __syncthreads();
  }
  int running = part[t] - sum;              // exclusive
  for (int i = 0; i < PER; i++) {
    int idx = base + i;
    if (idx < NN) {
      int c = cnt[idx];
      off[idx] = running;
      dinv[idx] = rsqrtf((float)(c + 1));
      running += c;
    }
  }
  if (t == 1023) off[NN] = running;         // == NE
}

// csr[off[dst] + slot] = src ; cnt used as countdown cursor (ends at 0)
__global__ void k_fill(const int* __restrict__ ei, const int* __restrict__ off,
                       int* __restrict__ cnt, int* __restrict__ csr) {
  int e = blockIdx.x * 256 + threadIdx.x;
  if (e >= NE) return;
  int s = ei[e], d = ei[NE + e];
  int slot = atomicAdd(&cnt[d], -1) - 1;
  csr[off[d] + slot] = s;
}

// x = feats @ W   (bf16 MFMA, f32 accumulate, f32 out)
__launch_bounds__(256, 2)
__global__ void k_gemm(const float* __restrict__ feats, const ushort* __restrict__ Wt,
                       float* __restrict__ x) {
  __shared__ ushort Abuf[128 * 64];         // row stride 128B, XOR-swizzled
  const int tid = threadIdx.x;
  const int lane = tid & 63;
  const int wid = tid >> 6;
  const int wr = wid >> 1, wc = wid & 1;
  const int rbase = blockIdx.x * 128;

  f32x4 acc[4][4];
#pragma unroll
  for (int a = 0; a < 4; a++)
#pragma unroll
    for (int b2 = 0; b2 < 4; b2++) acc[a][b2] = f32x4{0.f, 0.f, 0.f, 0.f};

  const int sr = tid >> 1;
  const int sk = (tid & 1) * 32;
  int grow = rbase + sr; if (grow > NN - 1) grow = NN - 1;
  const float* gsrc = feats + grow * KIN + sk;

  for (int ks = 0; ks < KIN; ks += 64) {
    f32x4 v[8];
#pragma unroll
    for (int q = 0; q < 8; q++) v[q] = *(const f32x4*)(gsrc + ks + q * 4);
    __syncthreads();
#pragma unroll
    for (int q8 = 0; q8 < 4; q8++) {
      s16x8 pk;
#pragma unroll
      for (int t2 = 0; t2 < 4; t2++) {
        pk[t2]     = (short)f2bf(v[2 * q8][t2]);
        pk[t2 + 4] = (short)f2bf(v[2 * q8 + 1][t2]);
      }
      int kb = (sk >> 3) + q8;
      int boff = sr * 128 + ((kb ^ (sr & 7)) << 4);
      *(s16x8*)((char*)Abuf + boff) = pk;
    }
    __syncthreads();
#pragma unroll
    for (int kk = 0; kk < 2; kk++) {
      s16x8 af[4];
#pragma unroll
      for (int mt = 0; mt < 4; mt++) {
        int r = wr * 64 + mt * 16 + (lane & 15);
        int kb = kk * 4 + (lane >> 4);
        af[mt] = *(const s16x8*)((const char*)Abuf + r * 128 + ((kb ^ (r & 7)) << 4));
      }
#pragma unroll
      for (int nt = 0; nt < 4; nt++) {
        int c = wc * 64 + nt * 16 + (lane & 15);
        const s16x8 bf = *(const s16x8*)(Wt + c * KIN + (ks + kk * 32 + (lane >> 4) * 8));
#pragma unroll
        for (int mt = 0; mt < 4; mt++)
          acc[mt][nt] = __builtin_amdgcn_mfma_f32_16x16x32_bf16(af[mt], bf, acc[mt][nt], 0, 0, 0);
      }
    }
  }
#pragma unroll
  for (int mt = 0; mt < 4; mt++) {
    int r0 = rbase + wr * 64 + mt * 16 + (lane >> 4) * 4;
#pragma unroll
    for (int nt = 0; nt < 4; nt++) {
      int c = wc * 64 + nt * 16 + (lane & 15);
#pragma unroll
      for (int j = 0; j < 4; j++) {
        int r = r0 + j;
        if (r < NN) x[r * HC + c] = acc[mt][nt][j];
      }
    }
  }
}

// one wave per node: out[n] = dropout(relu(self + sum_{e in CSR} x[src]*norm + b))
__global__ void k_agg(const float* __restrict__ x, const float* __restrict__ dinv,
                      const int* __restrict__ off, const int* __restrict__ csr,
                      const float* __restrict__ b, float* __restrict__ out) {
  int n = blockIdx.x * 4 + (threadIdx.x >> 6);
  if (n >= NN) return;
  const int lane = threadIdx.x & 63;
  const int beg = off[n], end = off[n + 1];
  const float dn = dinv[n];
  f32x2 bb = *(const f32x2*)(b + lane * 2);
  f32x2 sv = *(const f32x2*)(x + n * HC + lane * 2);
  float ax = sv.x * dn * dn + bb.x;
  float ay = sv.y * dn * dn + bb.y;
  for (int j = beg; j < end; j++) {
    int s = csr[j];                          // wave-uniform -> broadcast
    float nr = dinv[s] * dn;
    f32x2 xv = *(const f32x2*)(x + s * HC + lane * 2);
    ax += xv.x * nr;
    ay += xv.y * nr;
  }
  int i0 = n * HC + lane * 2;
  float vx = fmaxf(ax, 0.0f) * 2.0f;
  float vy = fmaxf(ay, 0.0f) * 2.0f;
  f32x2 r;
  r.x = (tf_bits((unsigned)i0)     >> 31) ? 0.0f : vx;
  r.y = (tf_bits((unsigned)i0 + 1) >> 31) ? 0.0f : vy;
  *(f32x2*)(out + i0) = r;
}

extern "C" void kernel_launch(void* const* d_in, const int* in_sizes, int n_in,
                              void* d_out, int out_size, void* d_ws, size_t ws_size,
                              hipStream_t stream) {
  const float* feats = (const float*)d_in[0];
  const float* W     = (const float*)d_in[1];
  const float* b     = (const float*)d_in[2];
  const int*   ei    = (const int*)d_in[3];
  float* out = (float*)d_out;

  // ws: x[NN*HC] f32 | Wt[HC*KIN] bf16 | dinv[NN] f32 | cnt[NN] i32 |
  //     off[NN+1] i32 | csr[NE] i32   (~29.5 MB)
  char* ws = (char*)d_ws;
  size_t o = 0;
  float*  x    = (float*)(ws + o);  o += ((size_t)NN * HC * 4 + 255) & ~(size_t)255;
  ushort* Wt   = (ushort*)(ws + o); o += ((size_t)HC * KIN * 2 + 255) & ~(size_t)255;
  float*  dinv = (float*)(ws + o);  o += ((size_t)NN * 4 + 255) & ~(size_t)255;
  int*    cnt  = (int*)(ws + o);    o += ((size_t)NN * 4 + 255) & ~(size_t)255;
  int*    off  = (int*)(ws + o);    o += ((size_t)(NN + 1) * 4 + 255) & ~(size_t)255;
  int*    csr  = (int*)(ws + o);

  k_prep<<<(KIN * HC + 255) / 256, 256, 0, stream>>>(W, cnt, Wt);
  k_cnt <<<(NE + 255) / 256, 256, 0, stream>>>(ei, cnt);
  k_scan<<<1, 1024, 0, stream>>>(cnt, off, dinv);
  k_fill<<<(NE + 255) / 256, 256, 0, stream>>>(ei, off, cnt, csr);
  k_gemm<<<(NN + 127) / 128, 256, 0, stream>>>(feats, Wt, x);
  k_agg <<<(NN + 3) / 4, 256, 0, stream>>>(x, dinv, off, csr, b, out);
}

// Round 3
// 222.092 us; speedup vs baseline: 3.4682x; 1.5199x over previous
//
#include <hip/hip_runtime.h>

#define NN 50000
#define NE 800000
#define KIN 512
#define HC 128
#define SCAN_NB ((NN + 255) / 256)   // 196

typedef float f32x4 __attribute__((ext_vector_type(4)));
typedef float f32x2 __attribute__((ext_vector_type(2)));
typedef short s16x8 __attribute__((ext_vector_type(8)));

__device__ __forceinline__ ushort f2bf(float f) {
  unsigned u = __float_as_uint(f);
  unsigned r = (u + 0x7FFFu + ((u >> 16) & 1u)) >> 16;  // RNE
  return (ushort)r;
}

// JAX threefry2x32-20, partitionable path: ctr=(0,i), key=(0,42), bits=o0^o1
__device__ __forceinline__ unsigned tf_bits(unsigned i) {
  unsigned x0 = 0u, x1 = i;
  const unsigned ks0 = 0u, ks1 = 42u, ks2 = 0x1BD11BDAu ^ 42u;
  x0 += ks0; x1 += ks1;
#define R(r) { x0 += x1; x1 = (x1 << r) | (x1 >> (32 - r)); x1 ^= x0; }
  R(13) R(15) R(26) R(6)
  x0 += ks1; x1 += ks2 + 1u;
  R(17) R(29) R(16) R(24)
  x0 += ks2; x1 += ks0 + 2u;
  R(13) R(15) R(26) R(6)
  x0 += ks0; x1 += ks1 + 3u;
  R(17) R(29) R(16) R(24)
  x0 += ks1; x1 += ks2 + 4u;
  R(13) R(15) R(26) R(6)
  x0 += ks2; x1 += ks0 + 5u;
#undef R
  return x0 ^ x1;
}

// zero edge-count + W transpose/convert: Wt[c][k] bf16
__global__ void k_prep(const float* __restrict__ W, int* __restrict__ cnt,
                       ushort* __restrict__ Wt) {
  int t = blockIdx.x * 256 + threadIdx.x;   // t < 65536
  if (t < NN) cnt[t] = 0;
  if (t < KIN * HC) {
    int c = t & (HC - 1), k = t >> 7;       // W row-major [k][c]
    Wt[c * KIN + k] = f2bf(W[t]);
  }
}

__global__ void k_cnt(const int* __restrict__ ei, int* __restrict__ cnt) {
  int e = blockIdx.x * 256 + threadIdx.x;
  if (e < NE) atomicAdd(&cnt[ei[NE + e]], 1);
}

// per-block exclusive scan of cnt; off = local exclusive, bsum[b] = block total
__global__ void k_scan1(const int* __restrict__ cnt, int* __restrict__ off,
                        float* __restrict__ dinv, int* __restrict__ bsum) {
  const int i = blockIdx.x * 256 + threadIdx.x;
  const int lane = threadIdx.x & 63, wid = threadIdx.x >> 6;
  int c = (i < NN) ? cnt[i] : 0;
  if (i < NN) dinv[i] = rsqrtf((float)(c + 1));
  int v = c;
#pragma unroll
  for (int d = 1; d < 64; d <<= 1) {
    int t = __shfl_up(v, d);
    if (lane >= d) v += t;
  }
  __shared__ int wsum[4];
  if (lane == 63) wsum[wid] = v;
  __syncthreads();
  int wadd = 0;
#pragma unroll
  for (int w = 0; w < 3; w++) if (w < wid) wadd += wsum[w];
  int incl = v + wadd;
  if (i < NN) off[i] = incl - c;            // block-local exclusive
  if (threadIdx.x == 255) bsum[blockIdx.x] = incl;
}

// exclusive scan of SCAN_NB (<=256) block sums, in place
__global__ void k_scan2(int* __restrict__ bsum) {
  const int t = threadIdx.x;
  const int lane = t & 63, wid = t >> 6;
  int c = (t < SCAN_NB) ? bsum[t] : 0;
  int v = c;
#pragma unroll
  for (int d = 1; d < 64; d <<= 1) {
    int u = __shfl_up(v, d);
    if (lane >= d) v += u;
  }
  __shared__ int wsum[4];
  if (lane == 63) wsum[wid] = v;
  __syncthreads();
  int wadd = 0;
#pragma unroll
  for (int w = 0; w < 3; w++) if (w < wid) wadd += wsum[w];
  if (t < SCAN_NB) bsum[t] = v + wadd - c;  // exclusive
}

__global__ void k_scan3(int* __restrict__ off, const int* __restrict__ bsum) {
  int i = blockIdx.x * 256 + threadIdx.x;
  if (i < NN) off[i] += bsum[blockIdx.x];
  if (i == 0) off[NN] = NE;                 // total degree == NE by construction
}

// csr[off[dst] + slot] = src ; cnt used as countdown cursor (ends at 0)
__global__ void k_fill(const int* __restrict__ ei, const int* __restrict__ off,
                       int* __restrict__ cnt, int* __restrict__ csr) {
  int e = blockIdx.x * 256 + threadIdx.x;
  if (e >= NE) return;
  int s = ei[e], d = ei[NE + e];
  int slot = atomicAdd(&cnt[d], -1) - 1;
  csr[off[d] + slot] = s;
}

// x = feats @ W   (bf16 MFMA, f32 accumulate, f32 out)
__launch_bounds__(256, 2)
__global__ void k_gemm(const float* __restrict__ feats, const ushort* __restrict__ Wt,
                       float* __restrict__ x) {
  __shared__ ushort Abuf[128 * 64];         // row stride 128B, XOR-swizzled
  const int tid = threadIdx.x;
  const int lane = tid & 63;
  const int wid = tid >> 6;
  const int wr = wid >> 1, wc = wid & 1;
  const int rbase = blockIdx.x * 128;

  f32x4 acc[4][4];
#pragma unroll
  for (int a = 0; a < 4; a++)
#pragma unroll
    for (int b2 = 0; b2 < 4; b2++) acc[a][b2] = f32x4{0.f, 0.f, 0.f, 0.f};

  const int sr = tid >> 1;
  const int sk = (tid & 1) * 32;
  int grow = rbase + sr; if (grow > NN - 1) grow = NN - 1;
  const float* gsrc = feats + grow * KIN + sk;

  for (int ks = 0; ks < KIN; ks += 64) {
    f32x4 v[8];
#pragma unroll
    for (int q = 0; q < 8; q++) v[q] = *(const f32x4*)(gsrc + ks + q * 4);
    __syncthreads();
#pragma unroll
    for (int q8 = 0; q8 < 4; q8++) {
      s16x8 pk;
#pragma unroll
      for (int t2 = 0; t2 < 4; t2++) {
        pk[t2]     = (short)f2bf(v[2 * q8][t2]);
        pk[t2 + 4] = (short)f2bf(v[2 * q8 + 1][t2]);
      }
      int kb = (sk >> 3) + q8;
      int boff = sr * 128 + ((kb ^ (sr & 7)) << 4);
      *(s16x8*)((char*)Abuf + boff) = pk;
    }
    __syncthreads();
#pragma unroll
    for (int kk = 0; kk < 2; kk++) {
      s16x8 af[4];
#pragma unroll
      for (int mt = 0; mt < 4; mt++) {
        int r = wr * 64 + mt * 16 + (lane & 15);
        int kb = kk * 4 + (lane >> 4);
        af[mt] = *(const s16x8*)((const char*)Abuf + r * 128 + ((kb ^ (r & 7)) << 4));
      }
#pragma unroll
      for (int nt = 0; nt < 4; nt++) {
        int c = wc * 64 + nt * 16 + (lane & 15);
        const s16x8 bf = *(const s16x8*)(Wt + c * KIN + (ks + kk * 32 + (lane >> 4) * 8));
#pragma unroll
        for (int mt = 0; mt < 4; mt++)
          acc[mt][nt] = __builtin_amdgcn_mfma_f32_16x16x32_bf16(af[mt], bf, acc[mt][nt], 0, 0, 0);
      }
    }
  }
#pragma unroll
  for (int mt = 0; mt < 4; mt++) {
    int r0 = rbase + wr * 64 + mt * 16 + (lane >> 4) * 4;
#pragma unroll
    for (int nt = 0; nt < 4; nt++) {
      int c = wc * 64 + nt * 16 + (lane & 15);
#pragma unroll
      for (int j = 0; j < 4; j++) {
        int r = r0 + j;
        if (r < NN) x[r * HC + c] = acc[mt][nt][j];
      }
    }
  }
}

// one wave per node: out[n] = dropout(relu(self + sum_{e in CSR} x[src]*norm + b))
__global__ void k_agg(const float* __restrict__ x, const float* __restrict__ dinv,
                      const int* __restrict__ off, const int* __restrict__ csr,
                      const float* __restrict__ b, float* __restrict__ out) {
  int n = blockIdx.x * 4 + (threadIdx.x >> 6);
  if (n >= NN) return;
  const int lane = threadIdx.x & 63;
  const int beg = off[n], end = off[n + 1];
  const float dn = dinv[n];
  f32x2 bb = *(const f32x2*)(b + lane * 2);
  f32x2 sv = *(const f32x2*)(x + n * HC + lane * 2);
  float ax = sv.x * dn * dn + bb.x;
  float ay = sv.y * dn * dn + bb.y;
  for (int j = beg; j < end; j++) {
    int s = csr[j];                          // wave-uniform -> broadcast
    float nr = dinv[s] * dn;
    f32x2 xv = *(const f32x2*)(x + s * HC + lane * 2);
    ax += xv.x * nr;
    ay += xv.y * nr;
  }
  int i0 = n * HC + lane * 2;
  float vx = fmaxf(ax, 0.0f) * 2.0f;
  float vy = fmaxf(ay, 0.0f) * 2.0f;
  f32x2 r;
  r.x = (tf_bits((unsigned)i0)     >> 31) ? 0.0f : vx;
  r.y = (tf_bits((unsigned)i0 + 1) >> 31) ? 0.0f : vy;
  *(f32x2*)(out + i0) = r;
}

extern "C" void kernel_launch(void* const* d_in, const int* in_sizes, int n_in,
                              void* d_out, int out_size, void* d_ws, size_t ws_size,
                              hipStream_t stream) {
  const float* feats = (const float*)d_in[0];
  const float* W     = (const float*)d_in[1];
  const float* b     = (const float*)d_in[2];
  const int*   ei    = (const int*)d_in[3];
  float* out = (float*)d_out;

  // ws: x[NN*HC] f32 | Wt[HC*KIN] bf16 | dinv[NN] f32 | cnt[NN] i32 |
  //     off[NN+1] i32 | bsum[256] i32 | csr[NE] i32
  char* ws = (char*)d_ws;
  size_t o = 0;
  float*  x    = (float*)(ws + o);  o += ((size_t)NN * HC * 4 + 255) & ~(size_t)255;
  ushort* Wt   = (ushort*)(ws + o); o += ((size_t)HC * KIN * 2 + 255) & ~(size_t)255;
  float*  dinv = (float*)(ws + o);  o += ((size_t)NN * 4 + 255) & ~(size_t)255;
  int*    cnt  = (int*)(ws + o);    o += ((size_t)NN * 4 + 255) & ~(size_t)255;
  int*    off  = (int*)(ws + o);    o += ((size_t)(NN + 1) * 4 + 255) & ~(size_t)255;
  int*    bsum = (int*)(ws + o);    o += 256 * 4;
  int*    csr  = (int*)(ws + o);

  k_prep <<<(KIN * HC + 255) / 256, 256, 0, stream>>>(W, cnt, Wt);
  k_cnt  <<<(NE + 255) / 256, 256, 0, stream>>>(ei, cnt);
  k_scan1<<<SCAN_NB, 256, 0, stream>>>(cnt, off, dinv, bsum);
  k_scan2<<<1, 256, 0, stream>>>(bsum);
  k_scan3<<<SCAN_NB, 256, 0, stream>>>(off, bsum);
  k_fill <<<(NE + 255) / 256, 256, 0, stream>>>(ei, off, cnt, csr);
  k_gemm <<<(NN + 127) / 128, 256, 0, stream>>>(feats, Wt, x);
  k_agg  <<<(NN + 3) / 4, 256, 0, stream>>>(x, dinv, off, csr, b, out);
}